// Round 1
// baseline (543.936 us; speedup 1.0000x reference)
//
#include <hip/hip_runtime.h>
#include <hip/hip_bf16.h>

typedef __attribute__((ext_vector_type(8))) short bf16x8;
typedef __attribute__((ext_vector_type(4))) float f32x4;

#define DCH 1024
#define SEQ 4096
#define NBATCH 8

// RNE float -> bf16 (finite inputs)
static __device__ __forceinline__ unsigned int f2bf(float f) {
    unsigned int u = __float_as_uint(f);
    return (u + 0x7fffu + ((u >> 16) & 1u)) >> 16;
}

// ---------------- transpose + convert Wk/Wv -> bf16 W^T[h][k] ----------------
__global__ __launch_bounds__(256) void wt_kernel(
    const float* __restrict__ Wk, const float* __restrict__ Wv,
    unsigned short* __restrict__ WkT, unsigned short* __restrict__ WvT)
{
    __shared__ float tile[32][33];
    const float* src = blockIdx.z ? Wv : Wk;
    unsigned short* dst = blockIdx.z ? WvT : WkT;
    int h0 = blockIdx.x * 32, k0 = blockIdx.y * 32;
    int tx = threadIdx.x, ty = threadIdx.y;
#pragma unroll
    for (int i = 0; i < 4; i++)
        tile[ty + i * 8][tx] = src[(size_t)(k0 + ty + i * 8) * DCH + h0 + tx];
    __syncthreads();
#pragma unroll
    for (int i = 0; i < 4; i++)
        dst[(size_t)(h0 + ty + i * 8) * DCH + k0 + tx] =
            (unsigned short)f2bf(tile[tx][ty + i * 8]);
}

// ---------------- fused K/V projection + fmap + per-channel reduction --------
// tile: 128 s x 128 h, BK=64, 512 threads = 8 waves (2 s-groups x 4 h-groups)
__global__ __launch_bounds__(512) void kv_gemm_kernel(
    const float* __restrict__ x,
    const unsigned short* __restrict__ WkT,
    const unsigned short* __restrict__ WvT,
    const float* __restrict__ bk,
    const float* __restrict__ bv,
    float* __restrict__ part)
{
    __shared__ unsigned short sA[128 * 64];
    __shared__ unsigned short sK[128 * 64];
    __shared__ unsigned short sV[128 * 64];
    __shared__ float red[2][128][2];

    // XCD swizzle: all 8 h-tiles of one (n,s_tile) land on the same XCD
    int b = blockIdx.x;
    int r = b & 7, j = b >> 3;
    int ns = r * 32 + (j >> 3);
    int h_tile = j & 7;
    int n = ns >> 5, s_tile = ns & 31;
    int s0 = s_tile * 128, h0 = h_tile * 128;

    const float* xA = x + ((size_t)(n * SEQ + s0)) * DCH;

    int tid = threadIdx.x;
    int lane = tid & 63, wid = tid >> 6;
    int wsg = wid >> 2, wh = wid & 3;   // wave s-group (0..1), wave h-group (0..3)
    int col = lane & 15, lhi = lane >> 4;

    f32x4 acck[4][2], accv[4][2];
#pragma unroll
    for (int mt = 0; mt < 4; mt++)
#pragma unroll
        for (int nt = 0; nt < 2; nt++) {
            acck[mt][nt] = (f32x4){0.f, 0.f, 0.f, 0.f};
            accv[mt][nt] = (f32x4){0.f, 0.f, 0.f, 0.f};
        }

    for (int kk = 0; kk < 16; kk++) {
        int k0 = kk * 64;
        // stage A (fp32 -> bf16), XOR-swizzled 16B groups
#pragma unroll
        for (int i = 0; i < 2; i++) {
            int c = tid + i * 512;
            int row = c >> 3, c8 = c & 7;
            const float4* p = (const float4*)(xA + (size_t)row * DCH + k0 + c8 * 8);
            float4 f0 = p[0], f1 = p[1];
            unsigned int p0 = f2bf(f0.x) | (f2bf(f0.y) << 16);
            unsigned int p1 = f2bf(f0.z) | (f2bf(f0.w) << 16);
            unsigned int p2 = f2bf(f1.x) | (f2bf(f1.y) << 16);
            unsigned int p3 = f2bf(f1.z) | (f2bf(f1.w) << 16);
            uint4 pk = {p0, p1, p2, p3};
            int g = c8 ^ (row & 7);
            *((uint4*)&sA[row * 64 + g * 8]) = pk;
        }
        // stage Bk, Bv (already bf16, [h][k])
#pragma unroll
        for (int i = 0; i < 2; i++) {
            int c = tid + i * 512;
            int row = c >> 3, c8 = c & 7;
            int g = c8 ^ (row & 7);
            *((uint4*)&sK[row * 64 + g * 8]) =
                *((const uint4*)(WkT + (size_t)(h0 + row) * DCH + k0 + c8 * 8));
            *((uint4*)&sV[row * 64 + g * 8]) =
                *((const uint4*)(WvT + (size_t)(h0 + row) * DCH + k0 + c8 * 8));
        }
        __syncthreads();
#pragma unroll
        for (int ks = 0; ks < 2; ks++) {
            bf16x8 af[4], bkf[2], bvf[2];
            int gg = ks * 4 + lhi;
#pragma unroll
            for (int mt = 0; mt < 4; mt++) {
                int rowa = wsg * 64 + mt * 16 + col;
                af[mt] = *((const bf16x8*)&sA[rowa * 64 + ((gg ^ (rowa & 7)) * 8)]);
            }
#pragma unroll
            for (int nt = 0; nt < 2; nt++) {
                int rowb = wh * 32 + nt * 16 + col;
                int o = rowb * 64 + ((gg ^ (rowb & 7)) * 8);
                bkf[nt] = *((const bf16x8*)&sK[o]);
                bvf[nt] = *((const bf16x8*)&sV[o]);
            }
#pragma unroll
            for (int mt = 0; mt < 4; mt++)
#pragma unroll
                for (int nt = 0; nt < 2; nt++) {
                    acck[mt][nt] = __builtin_amdgcn_mfma_f32_16x16x32_bf16(
                        af[mt], bkf[nt], acck[mt][nt], 0, 0, 0);
                    accv[mt][nt] = __builtin_amdgcn_mfma_f32_16x16x32_bf16(
                        af[mt], bvf[nt], accv[mt][nt], 0, 0, 0);
                }
        }
        __syncthreads();
    }

    // epilogue: fmap, pairwise product, reduce over the 128 s-rows of this tile
#pragma unroll
    for (int nt = 0; nt < 2; nt++) {
        int h_local = wh * 32 + nt * 16 + col;
        float bkv = bk[h0 + h_local];
        float bvv = bv[h0 + h_local];
        float pkv = 0.f, pks = 0.f;
#pragma unroll
        for (int mt = 0; mt < 4; mt++)
#pragma unroll
            for (int rr = 0; rr < 4; rr++) {
                float ck = acck[mt][nt][rr] + bkv;
                float cv = accv[mt][nt][rr] + bvv;
                float kq = ck > 0.f ? ck + 1.f : __expf(ck);  // elu+1
                pkv += kq * cv;
                pks += kq;
            }
        pkv += __shfl_xor(pkv, 16);
        pkv += __shfl_xor(pkv, 32);
        pks += __shfl_xor(pks, 16);
        pks += __shfl_xor(pks, 32);
        if (lhi == 0) {
            red[wsg][h_local][0] = pkv;
            red[wsg][h_local][1] = pks;
        }
    }
    __syncthreads();
    if (tid < 256) {
        int h = tid & 127, t = tid >> 7;
        float v = red[0][h][t] + red[1][h][t];
        part[(((size_t)(n * 8 + h_tile) * 2 + t) * 32 + s_tile) * 128 + h] = v;
    }
}

// ---------------- reduce partials -> V[n,h] = KV/Ksum ------------------------
__global__ __launch_bounds__(128) void reduce_kernel(
    const float* __restrict__ part, float* __restrict__ Vc)
{
    int g = blockIdx.x;   // n*8 + h_tile
    int h = threadIdx.x;  // 0..127
    const float* base = part + (size_t)g * 2 * 32 * 128;
    float kv = 0.f, ks = 0.f;
#pragma unroll 4
    for (int st = 0; st < 32; st++) {
        kv += base[st * 128 + h];
        ks += base[32 * 128 + st * 128 + h];
    }
    int n = g >> 3, ht = g & 7;
    Vc[n * DCH + ht * 128 + h] = kv / ks;
}

// ---------------- tiny fp32 GEMM: out_row = gelu(V @ Wo + bo) ----------------
__global__ __launch_bounds__(256) void out_gemm_kernel(
    const float* __restrict__ Vc, const float* __restrict__ Wo,
    const float* __restrict__ bo, float* __restrict__ out_row)
{
    __shared__ float vs[DCH];
    int n = blockIdx.x, ob = blockIdx.y;
    int tid = threadIdx.x;
    for (int i = tid; i < DCH; i += 256) vs[i] = Vc[n * DCH + i];
    __syncthreads();
    int o = ob * 256 + tid;
    float acc = bo[o];
#pragma unroll 8
    for (int h = 0; h < DCH; h++) acc += vs[h] * Wo[(size_t)h * DCH + o];
    float u = acc;
    float inner = 0.7978845608028654f * (u + 0.044715f * u * u * u);
    out_row[n * DCH + o] = 0.5f * u * (1.f + tanhf(inner));  // gelu approximate=True
}

// ---------------- broadcast out_row over S -----------------------------------
__global__ __launch_bounds__(256) void bcast_kernel(
    const float* __restrict__ out_row, float4* __restrict__ out)
{
    int n = blockIdx.x >> 6;
    int sc = blockIdx.x & 63;
    int tid = threadIdx.x;  // one float4 column
    float4 v = ((const float4*)out_row)[n * 256 + tid];
    size_t base = ((size_t)(n * SEQ) + (size_t)sc * 64) * 256 + tid;
#pragma unroll 4
    for (int s = 0; s < 64; s++)
        out[base + (size_t)s * 256] = v;
}

extern "C" void kernel_launch(void* const* d_in, const int* in_sizes, int n_in,
                              void* d_out, int out_size, void* d_ws, size_t ws_size,
                              hipStream_t stream) {
    const float* x  = (const float*)d_in[0];
    // Wq (d_in[1]) and bq (d_in[2]) are mathematically irrelevant: Q > 0 cancels
    // in V = Q*KV/(Q*Ksum + 1e-6) up to a <=5e-8 relative perturbation.
    const float* Wk = (const float*)d_in[3];
    const float* bk = (const float*)d_in[4];
    const float* Wv = (const float*)d_in[5];
    const float* bv = (const float*)d_in[6];
    const float* Wo = (const float*)d_in[7];
    const float* bo = (const float*)d_in[8];

    char* ws = (char*)d_ws;
    unsigned short* WkT = (unsigned short*)ws;                 // 2 MB bf16 [h][k]
    unsigned short* WvT = WkT + 1024 * 1024;                   // 2 MB
    float* part = (float*)(ws + 4 * 1024 * 1024);              // 2 MB partials
    float* Vc   = part + 8 * 8 * 2 * 32 * 128;                 // 32 KB
    float* out_row = Vc + 8 * 1024;                            // 32 KB

    wt_kernel<<<dim3(32, 32, 2), dim3(32, 8), 0, stream>>>(Wk, Wv, WkT, WvT);
    kv_gemm_kernel<<<2048, 512, 0, stream>>>(x, WkT, WvT, bk, bv, part);
    reduce_kernel<<<64, 128, 0, stream>>>(part, Vc);
    out_gemm_kernel<<<dim3(8, 4), 256, 0, stream>>>(Vc, Wo, bo, out_row);
    bcast_kernel<<<512, 256, 0, stream>>>(out_row, (float4*)d_out);
}

// Round 2
// 460.650 us; speedup vs baseline: 1.1808x; 1.1808x over previous
//
#include <hip/hip_runtime.h>
#include <hip/hip_bf16.h>

typedef __attribute__((ext_vector_type(8))) short bf16x8;
typedef __attribute__((ext_vector_type(4))) float f32x4;

#define GLOBAL_AS __attribute__((address_space(1)))
#define LDS_AS __attribute__((address_space(3)))

#define DCH 1024
#define SEQ 4096
#define NBATCH 8

// RNE float -> bf16 (finite inputs)
static __device__ __forceinline__ unsigned int f2bf(float f) {
    unsigned int u = __float_as_uint(f);
    return (u + 0x7fffu + ((u >> 16) & 1u)) >> 16;
}

static __device__ __forceinline__ void async_copy16(const void* g, void* l) {
    __builtin_amdgcn_global_load_lds((const GLOBAL_AS void*)g, (LDS_AS void*)l, 16, 0, 0);
}

// ---------------- x fp32 -> bf16 (once; amortized over 8 h-tile re-reads) ----
__global__ __launch_bounds__(256) void cvt_kernel(
    const float4* __restrict__ x, uint4* __restrict__ xb)
{
    size_t t = (size_t)blockIdx.x * 256 + threadIdx.x;  // 2M threads, 16 floats each
    const float4* p = x + t * 4;
    float4 f0 = p[0], f1 = p[1], f2 = p[2], f3 = p[3];
    uint4 a, b;
    a.x = f2bf(f0.x) | (f2bf(f0.y) << 16);
    a.y = f2bf(f0.z) | (f2bf(f0.w) << 16);
    a.z = f2bf(f1.x) | (f2bf(f1.y) << 16);
    a.w = f2bf(f1.z) | (f2bf(f1.w) << 16);
    b.x = f2bf(f2.x) | (f2bf(f2.y) << 16);
    b.y = f2bf(f2.z) | (f2bf(f2.w) << 16);
    b.z = f2bf(f3.x) | (f2bf(f3.y) << 16);
    b.w = f2bf(f3.z) | (f2bf(f3.w) << 16);
    xb[t * 2] = a;
    xb[t * 2 + 1] = b;
}

// ---------------- transpose + convert Wk/Wv -> bf16 W^T[h][k] ----------------
__global__ __launch_bounds__(256) void wt_kernel(
    const float* __restrict__ Wk, const float* __restrict__ Wv,
    unsigned short* __restrict__ WkT, unsigned short* __restrict__ WvT)
{
    __shared__ float tile[32][33];
    const float* src = blockIdx.z ? Wv : Wk;
    unsigned short* dst = blockIdx.z ? WvT : WkT;
    int h0 = blockIdx.x * 32, k0 = blockIdx.y * 32;
    int tx = threadIdx.x, ty = threadIdx.y;
#pragma unroll
    for (int i = 0; i < 4; i++)
        tile[ty + i * 8][tx] = src[(size_t)(k0 + ty + i * 8) * DCH + h0 + tx];
    __syncthreads();
#pragma unroll
    for (int i = 0; i < 4; i++)
        dst[(size_t)(h0 + ty + i * 8) * DCH + k0 + tx] =
            (unsigned short)f2bf(tile[tx][ty + i * 8]);
}

// ---------------- fast path: fused K/V projection + fmap + reduction ---------
// tile: 128 s x 128 h, BK=64, 512 threads = 8 waves. A/K/V staged via
// global_load_lds(16B); XOR swizzle applied on the SOURCE column so the
// linear lane-order LDS fill is pre-swizzled -> conflict-free ds_read_b128.
__global__ __launch_bounds__(512) void kv_gemm_fast(
    const unsigned short* __restrict__ xb,
    const unsigned short* __restrict__ WkT,
    const unsigned short* __restrict__ WvT,
    const float* __restrict__ bk,
    const float* __restrict__ bv,
    float* __restrict__ part)
{
    __shared__ unsigned short sA[128 * 64];
    __shared__ unsigned short sK[128 * 64];
    __shared__ unsigned short sV[128 * 64];
    __shared__ float red[2][128][2];

    // XCD swizzle: all 8 h-tiles of one (n,s_tile) land on the same XCD
    int b = blockIdx.x;
    int r = b & 7, j = b >> 3;
    int ns = r * 32 + (j >> 3);
    int h_tile = j & 7;
    int n = ns >> 5, s_tile = ns & 31;
    int s0 = s_tile * 128, h0 = h_tile * 128;

    int tid = threadIdx.x;
    int lane = tid & 63, wid = tid >> 6;
    int wsg = wid >> 2, wh = wid & 3;
    int col = lane & 15, lhi = lane >> 4;

    // staging geometry: chunk = (wid*2+i)*64 + lane, i in {0,1}
    int chunk0 = wid * 128 + lane;
    int chunk1 = chunk0 + 64;
    int row0 = chunk0 >> 3, c80 = (chunk0 & 7) ^ (row0 & 7);
    int row1 = chunk1 >> 3, c81 = (chunk1 & 7) ^ (row1 & 7);

    const unsigned short* gA0 = xb + (size_t)(n * SEQ + s0 + row0) * DCH + c80 * 8;
    const unsigned short* gA1 = xb + (size_t)(n * SEQ + s0 + row1) * DCH + c81 * 8;
    const unsigned short* gK0 = WkT + (size_t)(h0 + row0) * DCH + c80 * 8;
    const unsigned short* gK1 = WkT + (size_t)(h0 + row1) * DCH + c81 * 8;
    const unsigned short* gV0 = WvT + (size_t)(h0 + row0) * DCH + c80 * 8;
    const unsigned short* gV1 = WvT + (size_t)(h0 + row1) * DCH + c81 * 8;

    unsigned short* lA0 = &sA[(wid * 2 + 0) * 512];
    unsigned short* lA1 = &sA[(wid * 2 + 1) * 512];
    unsigned short* lK0 = &sK[(wid * 2 + 0) * 512];
    unsigned short* lK1 = &sK[(wid * 2 + 1) * 512];
    unsigned short* lV0 = &sV[(wid * 2 + 0) * 512];
    unsigned short* lV1 = &sV[(wid * 2 + 1) * 512];

    f32x4 acck[4][2], accv[4][2];
#pragma unroll
    for (int mt = 0; mt < 4; mt++)
#pragma unroll
        for (int nt = 0; nt < 2; nt++) {
            acck[mt][nt] = (f32x4){0.f, 0.f, 0.f, 0.f};
            accv[mt][nt] = (f32x4){0.f, 0.f, 0.f, 0.f};
        }

    for (int kk = 0; kk < 16; kk++) {
        int k0 = kk * 64;
        async_copy16(gA0 + k0, lA0);
        async_copy16(gA1 + k0, lA1);
        async_copy16(gK0 + k0, lK0);
        async_copy16(gK1 + k0, lK1);
        async_copy16(gV0 + k0, lV0);
        async_copy16(gV1 + k0, lV1);
        __syncthreads();
#pragma unroll
        for (int ks = 0; ks < 2; ks++) {
            bf16x8 af[4], bkf[2], bvf[2];
            int gg = ks * 4 + lhi;
#pragma unroll
            for (int mt = 0; mt < 4; mt++) {
                int rowa = wsg * 64 + mt * 16 + col;
                af[mt] = *((const bf16x8*)&sA[rowa * 64 + ((gg ^ (rowa & 7)) * 8)]);
            }
#pragma unroll
            for (int nt = 0; nt < 2; nt++) {
                int rowb = wh * 32 + nt * 16 + col;
                int o = rowb * 64 + ((gg ^ (rowb & 7)) * 8);
                bkf[nt] = *((const bf16x8*)&sK[o]);
                bvf[nt] = *((const bf16x8*)&sV[o]);
            }
#pragma unroll
            for (int mt = 0; mt < 4; mt++)
#pragma unroll
                for (int nt = 0; nt < 2; nt++) {
                    acck[mt][nt] = __builtin_amdgcn_mfma_f32_16x16x32_bf16(
                        af[mt], bkf[nt], acck[mt][nt], 0, 0, 0);
                    accv[mt][nt] = __builtin_amdgcn_mfma_f32_16x16x32_bf16(
                        af[mt], bvf[nt], accv[mt][nt], 0, 0, 0);
                }
        }
        __syncthreads();
    }

    // epilogue: fmap, pairwise product, reduce over the 128 s-rows of this tile
#pragma unroll
    for (int nt = 0; nt < 2; nt++) {
        int h_local = wh * 32 + nt * 16 + col;
        float bkv = bk[h0 + h_local];
        float bvv = bv[h0 + h_local];
        float pkv = 0.f, pks = 0.f;
#pragma unroll
        for (int mt = 0; mt < 4; mt++)
#pragma unroll
            for (int rr = 0; rr < 4; rr++) {
                float ck = acck[mt][nt][rr] + bkv;
                float cv = accv[mt][nt][rr] + bvv;
                float kq = ck > 0.f ? ck + 1.f : __expf(ck);  // elu+1
                pkv += kq * cv;
                pks += kq;
            }
        pkv += __shfl_xor(pkv, 16);
        pkv += __shfl_xor(pkv, 32);
        pks += __shfl_xor(pks, 16);
        pks += __shfl_xor(pks, 32);
        if (lhi == 0) {
            red[wsg][h_local][0] = pkv;
            red[wsg][h_local][1] = pks;
        }
    }
    __syncthreads();
    if (tid < 256) {
        int h = tid & 127, t = tid >> 7;
        float v = red[0][h][t] + red[1][h][t];
        part[(((size_t)(n * 8 + h_tile) * 2 + t) * 32 + s_tile) * 128 + h] = v;
    }
}

// ---------------- slow fallback (round-1 kernel, fp32 staging) ---------------
__global__ __launch_bounds__(512) void kv_gemm_slow(
    const float* __restrict__ x,
    const unsigned short* __restrict__ WkT,
    const unsigned short* __restrict__ WvT,
    const float* __restrict__ bk,
    const float* __restrict__ bv,
    float* __restrict__ part)
{
    __shared__ unsigned short sA[128 * 64];
    __shared__ unsigned short sK[128 * 64];
    __shared__ unsigned short sV[128 * 64];
    __shared__ float red[2][128][2];

    int b = blockIdx.x;
    int r = b & 7, j = b >> 3;
    int ns = r * 32 + (j >> 3);
    int h_tile = j & 7;
    int n = ns >> 5, s_tile = ns & 31;
    int s0 = s_tile * 128, h0 = h_tile * 128;

    const float* xA = x + ((size_t)(n * SEQ + s0)) * DCH;

    int tid = threadIdx.x;
    int lane = tid & 63, wid = tid >> 6;
    int wsg = wid >> 2, wh = wid & 3;
    int col = lane & 15, lhi = lane >> 4;

    f32x4 acck[4][2], accv[4][2];
#pragma unroll
    for (int mt = 0; mt < 4; mt++)
#pragma unroll
        for (int nt = 0; nt < 2; nt++) {
            acck[mt][nt] = (f32x4){0.f, 0.f, 0.f, 0.f};
            accv[mt][nt] = (f32x4){0.f, 0.f, 0.f, 0.f};
        }

    for (int kk = 0; kk < 16; kk++) {
        int k0 = kk * 64;
#pragma unroll
        for (int i = 0; i < 2; i++) {
            int c = tid + i * 512;
            int row = c >> 3, c8 = c & 7;
            const float4* p = (const float4*)(xA + (size_t)row * DCH + k0 + c8 * 8);
            float4 f0 = p[0], f1 = p[1];
            unsigned int p0 = f2bf(f0.x) | (f2bf(f0.y) << 16);
            unsigned int p1 = f2bf(f0.z) | (f2bf(f0.w) << 16);
            unsigned int p2 = f2bf(f1.x) | (f2bf(f1.y) << 16);
            unsigned int p3 = f2bf(f1.z) | (f2bf(f1.w) << 16);
            uint4 pk = {p0, p1, p2, p3};
            int g = c8 ^ (row & 7);
            *((uint4*)&sA[row * 64 + g * 8]) = pk;
        }
#pragma unroll
        for (int i = 0; i < 2; i++) {
            int c = tid + i * 512;
            int row = c >> 3, c8 = c & 7;
            int g = c8 ^ (row & 7);
            *((uint4*)&sK[row * 64 + g * 8]) =
                *((const uint4*)(WkT + (size_t)(h0 + row) * DCH + k0 + c8 * 8));
            *((uint4*)&sV[row * 64 + g * 8]) =
                *((const uint4*)(WvT + (size_t)(h0 + row) * DCH + k0 + c8 * 8));
        }
        __syncthreads();
#pragma unroll
        for (int ks = 0; ks < 2; ks++) {
            bf16x8 af[4], bkf[2], bvf[2];
            int gg = ks * 4 + lhi;
#pragma unroll
            for (int mt = 0; mt < 4; mt++) {
                int rowa = wsg * 64 + mt * 16 + col;
                af[mt] = *((const bf16x8*)&sA[rowa * 64 + ((gg ^ (rowa & 7)) * 8)]);
            }
#pragma unroll
            for (int nt = 0; nt < 2; nt++) {
                int rowb = wh * 32 + nt * 16 + col;
                int o = rowb * 64 + ((gg ^ (rowb & 7)) * 8);
                bkf[nt] = *((const bf16x8*)&sK[o]);
                bvf[nt] = *((const bf16x8*)&sV[o]);
            }
#pragma unroll
            for (int mt = 0; mt < 4; mt++)
#pragma unroll
                for (int nt = 0; nt < 2; nt++) {
                    acck[mt][nt] = __builtin_amdgcn_mfma_f32_16x16x32_bf16(
                        af[mt], bkf[nt], acck[mt][nt], 0, 0, 0);
                    accv[mt][nt] = __builtin_amdgcn_mfma_f32_16x16x32_bf16(
                        af[mt], bvf[nt], accv[mt][nt], 0, 0, 0);
                }
        }
        __syncthreads();
    }

#pragma unroll
    for (int nt = 0; nt < 2; nt++) {
        int h_local = wh * 32 + nt * 16 + col;
        float bkv = bk[h0 + h_local];
        float bvv = bv[h0 + h_local];
        float pkv = 0.f, pks = 0.f;
#pragma unroll
        for (int mt = 0; mt < 4; mt++)
#pragma unroll
            for (int rr = 0; rr < 4; rr++) {
                float ck = acck[mt][nt][rr] + bkv;
                float cv = accv[mt][nt][rr] + bvv;
                float kq = ck > 0.f ? ck + 1.f : __expf(ck);
                pkv += kq * cv;
                pks += kq;
            }
        pkv += __shfl_xor(pkv, 16);
        pkv += __shfl_xor(pkv, 32);
        pks += __shfl_xor(pks, 16);
        pks += __shfl_xor(pks, 32);
        if (lhi == 0) {
            red[wsg][h_local][0] = pkv;
            red[wsg][h_local][1] = pks;
        }
    }
    __syncthreads();
    if (tid < 256) {
        int h = tid & 127, t = tid >> 7;
        float v = red[0][h][t] + red[1][h][t];
        part[(((size_t)(n * 8 + h_tile) * 2 + t) * 32 + s_tile) * 128 + h] = v;
    }
}

// ---------------- reduce partials -> V[n,h] = KV/Ksum ------------------------
__global__ __launch_bounds__(128) void reduce_kernel(
    const float* __restrict__ part, float* __restrict__ Vc)
{
    int g = blockIdx.x;   // n*8 + h_tile
    int h = threadIdx.x;  // 0..127
    const float* base = part + (size_t)g * 2 * 32 * 128;
    float kv = 0.f, ks = 0.f;
#pragma unroll 4
    for (int st = 0; st < 32; st++) {
        kv += base[st * 128 + h];
        ks += base[32 * 128 + st * 128 + h];
    }
    int n = g >> 3, ht = g & 7;
    Vc[n * DCH + ht * 128 + h] = kv / ks;
}

// ---------------- out = gelu(V @ Wo + bo): k-split partial GEMM --------------
__global__ __launch_bounds__(256) void out_part_kernel(
    const float* __restrict__ Vc, const float* __restrict__ Wo,
    float* __restrict__ part2)
{
    __shared__ float vs[128];
    int n = blockIdx.x, kc = blockIdx.y, ob = blockIdx.z;
    int tid = threadIdx.x;
    if (tid < 128) vs[tid] = Vc[n * DCH + kc * 128 + tid];
    __syncthreads();
    int o = ob * 256 + tid;
    float acc = 0.f;
#pragma unroll 8
    for (int k = 0; k < 128; k++)
        acc += vs[k] * Wo[(size_t)(kc * 128 + k) * DCH + o];
    part2[(size_t)(n * 8 + kc) * DCH + o] = acc;
}

__global__ __launch_bounds__(256) void finish_kernel(
    const float* __restrict__ part2, const float* __restrict__ bo,
    float* __restrict__ out_row)
{
    int n = blockIdx.x, ob = blockIdx.y;
    int o = ob * 256 + threadIdx.x;
    float acc = bo[o];
#pragma unroll
    for (int kc = 0; kc < 8; kc++) acc += part2[(size_t)(n * 8 + kc) * DCH + o];
    float u = acc;
    float inner = 0.7978845608028654f * (u + 0.044715f * u * u * u);
    out_row[n * DCH + o] = 0.5f * u * (1.f + tanhf(inner));  // gelu approximate=True
}

// ---------------- broadcast out_row over S -----------------------------------
__global__ __launch_bounds__(256) void bcast_kernel(
    const float* __restrict__ out_row, float4* __restrict__ out)
{
    int n = blockIdx.x >> 7;
    int sc = blockIdx.x & 127;
    int tid = threadIdx.x;  // one float4 column
    float4 v = ((const float4*)out_row)[n * 256 + tid];
    size_t base = ((size_t)(n * SEQ) + (size_t)sc * 32) * 256 + tid;
#pragma unroll 4
    for (int s = 0; s < 32; s++)
        out[base + (size_t)s * 256] = v;
}

extern "C" void kernel_launch(void* const* d_in, const int* in_sizes, int n_in,
                              void* d_out, int out_size, void* d_ws, size_t ws_size,
                              hipStream_t stream) {
    const float* x  = (const float*)d_in[0];
    // Wq (d_in[1]) / bq (d_in[2]) cancel: Q>0 in V = Q*KV/(Q*Ksum + 1e-6)
    // up to <=5e-8 relative perturbation (validated: absmax 2.4e-4).
    const float* Wk = (const float*)d_in[3];
    const float* bk = (const float*)d_in[4];
    const float* Wv = (const float*)d_in[5];
    const float* bv = (const float*)d_in[6];
    const float* Wo = (const float*)d_in[7];
    const float* bo = (const float*)d_in[8];

    const size_t XB_BYTES = (size_t)NBATCH * SEQ * DCH * 2;   // 64 MB
    const size_t FAST_NEED = XB_BYTES + (2u << 20) * 2 + (2u << 20) + 262144 + 65536;
    bool fast = ws_size >= FAST_NEED;

    char* ws = (char*)d_ws;
    unsigned short* xb = (unsigned short*)ws;                  // fast path only
    char* base = fast ? ws + XB_BYTES : ws;
    unsigned short* WkT = (unsigned short*)base;               // 2 MB bf16 [h][k]
    unsigned short* WvT = WkT + 1024 * 1024;                   // 2 MB
    float* part  = (float*)(base + 4 * 1024 * 1024);           // 2 MB partials
    float* part2 = part + 8 * 8 * 2 * 32 * 128;                // 256 KB
    float* Vc    = part2 + 8 * 8 * 1024;                       // 32 KB
    float* out_row = Vc + 8 * 1024;                            // 32 KB

    wt_kernel<<<dim3(32, 32, 2), dim3(32, 8), 0, stream>>>(Wk, Wv, WkT, WvT);
    if (fast) {
        cvt_kernel<<<8192, 256, 0, stream>>>((const float4*)x, (uint4*)xb);
        kv_gemm_fast<<<2048, 512, 0, stream>>>(xb, WkT, WvT, bk, bv, part);
    } else {
        kv_gemm_slow<<<2048, 512, 0, stream>>>(x, WkT, WvT, bk, bv, part);
    }
    reduce_kernel<<<64, 128, 0, stream>>>(part, Vc);
    out_part_kernel<<<dim3(8, 8, 4), 256, 0, stream>>>(Vc, Wo, part2);
    finish_kernel<<<dim3(8, 4), 256, 0, stream>>>(part2, bo, out_row);
    bcast_kernel<<<1024, 256, 0, stream>>>(out_row, (float4*)d_out);
}

// Round 4
// 454.283 us; speedup vs baseline: 1.1973x; 1.0140x over previous
//
#include <hip/hip_runtime.h>
#include <hip/hip_bf16.h>

typedef __attribute__((ext_vector_type(8))) short bf16x8;
typedef __attribute__((ext_vector_type(4))) float f32x4;

#define GLOBAL_AS __attribute__((address_space(1)))
#define LDS_AS __attribute__((address_space(3)))

#define DCH 1024
#define SEQ 4096
#define NBATCH 8

// RNE float -> bf16 (finite inputs)
static __device__ __forceinline__ unsigned int f2bf(float f) {
    unsigned int u = __float_as_uint(f);
    return (u + 0x7fffu + ((u >> 16) & 1u)) >> 16;
}

static __device__ __forceinline__ void async_copy16(const void* g, void* l) {
    __builtin_amdgcn_global_load_lds((const GLOBAL_AS void*)g, (LDS_AS void*)l, 16, 0, 0);
}

static __device__ __forceinline__ float gelu_tanh(float u) {
    float inner = 0.7978845608028654f * (u + 0.044715f * u * u * u);
    return 0.5f * u * (1.f + tanhf(inner));  // gelu approximate=True
}

// ---------------- x fp32 -> bf16 (once; amortized over 8 h-tile re-reads) ----
__global__ __launch_bounds__(256) void cvt_kernel(
    const float4* __restrict__ x, uint4* __restrict__ xb)
{
    size_t t = (size_t)blockIdx.x * 256 + threadIdx.x;  // 4M threads, 8 floats each
    float4 f0 = x[t * 2], f1 = x[t * 2 + 1];
    uint4 a;
    a.x = f2bf(f0.x) | (f2bf(f0.y) << 16);
    a.y = f2bf(f0.z) | (f2bf(f0.w) << 16);
    a.z = f2bf(f1.x) | (f2bf(f1.y) << 16);
    a.w = f2bf(f1.z) | (f2bf(f1.w) << 16);
    xb[t] = a;
}

// ---------------- transpose + convert Wk/Wv -> bf16 W^T[h][k] ----------------
__global__ __launch_bounds__(256) void wt_kernel(
    const float* __restrict__ Wk, const float* __restrict__ Wv,
    unsigned short* __restrict__ WkT, unsigned short* __restrict__ WvT)
{
    __shared__ float tile[32][33];
    const float* src = blockIdx.z ? Wv : Wk;
    unsigned short* dst = blockIdx.z ? WvT : WkT;
    int h0 = blockIdx.x * 32, k0 = blockIdx.y * 32;
    int tx = threadIdx.x, ty = threadIdx.y;
#pragma unroll
    for (int i = 0; i < 4; i++)
        tile[ty + i * 8][tx] = src[(size_t)(k0 + ty + i * 8) * DCH + h0 + tx];
    __syncthreads();
#pragma unroll
    for (int i = 0; i < 4; i++)
        dst[(size_t)(h0 + ty + i * 8) * DCH + k0 + tx] =
            (unsigned short)f2bf(tile[tx][ty + i * 8]);
}

// ---------------- fast path: fused K/V projection + fmap + reduction ---------
// EXACT round-2 verified structure: tile 128 s x 128 h, BK=64, 512 threads =
// 8 waves. A/K/V ALL staged via global_load_lds(16B) with source-column XOR
// swizzle (pre-swizzled LDS fill -> conflict-free ds_read_b128). No plain
// global loads mixed into the vmcnt queue around the barriers (the round-3
// direct-B variant raced intermittently under graph replay).
__global__ __launch_bounds__(512) void kv_gemm_fast(
    const unsigned short* __restrict__ xb,
    const unsigned short* __restrict__ WkT,
    const unsigned short* __restrict__ WvT,
    const float* __restrict__ bk,
    const float* __restrict__ bv,
    float* __restrict__ part)
{
    __shared__ unsigned short sA[128 * 64];
    __shared__ unsigned short sK[128 * 64];
    __shared__ unsigned short sV[128 * 64];
    __shared__ float red[2][128][2];

    // XCD swizzle: all 8 h-tiles of one (n,s_tile) land on the same XCD
    int b = blockIdx.x;
    int r = b & 7, j = b >> 3;
    int ns = r * 32 + (j >> 3);
    int h_tile = j & 7;
    int n = ns >> 5, s_tile = ns & 31;
    int s0 = s_tile * 128, h0 = h_tile * 128;

    int tid = threadIdx.x;
    int lane = tid & 63, wid = tid >> 6;
    int wsg = wid >> 2, wh = wid & 3;
    int col = lane & 15, lhi = lane >> 4;

    // staging geometry: chunk = (wid*2+i)*64 + lane, i in {0,1}
    int chunk0 = wid * 128 + lane;
    int chunk1 = chunk0 + 64;
    int row0 = chunk0 >> 3, c80 = (chunk0 & 7) ^ (row0 & 7);
    int row1 = chunk1 >> 3, c81 = (chunk1 & 7) ^ (row1 & 7);

    const unsigned short* gA0 = xb + (size_t)(n * SEQ + s0 + row0) * DCH + c80 * 8;
    const unsigned short* gA1 = xb + (size_t)(n * SEQ + s0 + row1) * DCH + c81 * 8;
    const unsigned short* gK0 = WkT + (size_t)(h0 + row0) * DCH + c80 * 8;
    const unsigned short* gK1 = WkT + (size_t)(h0 + row1) * DCH + c81 * 8;
    const unsigned short* gV0 = WvT + (size_t)(h0 + row0) * DCH + c80 * 8;
    const unsigned short* gV1 = WvT + (size_t)(h0 + row1) * DCH + c81 * 8;

    unsigned short* lA0 = &sA[(wid * 2 + 0) * 512];
    unsigned short* lA1 = &sA[(wid * 2 + 1) * 512];
    unsigned short* lK0 = &sK[(wid * 2 + 0) * 512];
    unsigned short* lK1 = &sK[(wid * 2 + 1) * 512];
    unsigned short* lV0 = &sV[(wid * 2 + 0) * 512];
    unsigned short* lV1 = &sV[(wid * 2 + 1) * 512];

    f32x4 acck[4][2], accv[4][2];
#pragma unroll
    for (int mt = 0; mt < 4; mt++)
#pragma unroll
        for (int nt = 0; nt < 2; nt++) {
            acck[mt][nt] = (f32x4){0.f, 0.f, 0.f, 0.f};
            accv[mt][nt] = (f32x4){0.f, 0.f, 0.f, 0.f};
        }

    for (int kk = 0; kk < 16; kk++) {
        int k0 = kk * 64;
        async_copy16(gA0 + k0, lA0);
        async_copy16(gA1 + k0, lA1);
        async_copy16(gK0 + k0, lK0);
        async_copy16(gK1 + k0, lK1);
        async_copy16(gV0 + k0, lV0);
        async_copy16(gV1 + k0, lV1);
        __syncthreads();
#pragma unroll
        for (int ks = 0; ks < 2; ks++) {
            bf16x8 af[4], bkf[2], bvf[2];
            int gg = ks * 4 + lhi;
#pragma unroll
            for (int mt = 0; mt < 4; mt++) {
                int rowa = wsg * 64 + mt * 16 + col;
                af[mt] = *((const bf16x8*)&sA[rowa * 64 + ((gg ^ (rowa & 7)) * 8)]);
            }
#pragma unroll
            for (int nt = 0; nt < 2; nt++) {
                int rowb = wh * 32 + nt * 16 + col;
                int o = rowb * 64 + ((gg ^ (rowb & 7)) * 8);
                bkf[nt] = *((const bf16x8*)&sK[o]);
                bvf[nt] = *((const bf16x8*)&sV[o]);
            }
#pragma unroll
            for (int mt = 0; mt < 4; mt++)
#pragma unroll
                for (int nt = 0; nt < 2; nt++) {
                    acck[mt][nt] = __builtin_amdgcn_mfma_f32_16x16x32_bf16(
                        af[mt], bkf[nt], acck[mt][nt], 0, 0, 0);
                    accv[mt][nt] = __builtin_amdgcn_mfma_f32_16x16x32_bf16(
                        af[mt], bvf[nt], accv[mt][nt], 0, 0, 0);
                }
        }
        __syncthreads();
    }

    // epilogue: fmap, pairwise product, reduce over the 128 s-rows of this tile
#pragma unroll
    for (int nt = 0; nt < 2; nt++) {
        int h_local = wh * 32 + nt * 16 + col;
        float bkv = bk[h0 + h_local];
        float bvv = bv[h0 + h_local];
        float pkv = 0.f, pks = 0.f;
#pragma unroll
        for (int mt = 0; mt < 4; mt++)
#pragma unroll
            for (int rr = 0; rr < 4; rr++) {
                float ck = acck[mt][nt][rr] + bkv;
                float cv = accv[mt][nt][rr] + bvv;
                float kq = ck > 0.f ? ck + 1.f : __expf(ck);  // elu+1
                pkv += kq * cv;
                pks += kq;
            }
        pkv += __shfl_xor(pkv, 16);
        pkv += __shfl_xor(pkv, 32);
        pks += __shfl_xor(pks, 16);
        pks += __shfl_xor(pks, 32);
        if (lhi == 0) {
            red[wsg][h_local][0] = pkv;
            red[wsg][h_local][1] = pks;
        }
    }
    __syncthreads();
    if (tid < 256) {
        int h = tid & 127, t = tid >> 7;
        float v = red[0][h][t] + red[1][h][t];
        part[(((size_t)(n * 8 + h_tile) * 2 + t) * 32 + s_tile) * 128 + h] = v;
    }
}

// ---------------- slow fallback (fp32 staging, no xb needed) -----------------
__global__ __launch_bounds__(512) void kv_gemm_slow(
    const float* __restrict__ x,
    const unsigned short* __restrict__ WkT,
    const unsigned short* __restrict__ WvT,
    const float* __restrict__ bk,
    const float* __restrict__ bv,
    float* __restrict__ part)
{
    __shared__ unsigned short sA[128 * 64];
    __shared__ unsigned short sK[128 * 64];
    __shared__ unsigned short sV[128 * 64];
    __shared__ float red[2][128][2];

    int b = blockIdx.x;
    int r = b & 7, j = b >> 3;
    int ns = r * 32 + (j >> 3);
    int h_tile = j & 7;
    int n = ns >> 5, s_tile = ns & 31;
    int s0 = s_tile * 128, h0 = h_tile * 128;

    const float* xA = x + ((size_t)(n * SEQ + s0)) * DCH;

    int tid = threadIdx.x;
    int lane = tid & 63, wid = tid >> 6;
    int wsg = wid >> 2, wh = wid & 3;
    int col = lane & 15, lhi = lane >> 4;

    f32x4 acck[4][2], accv[4][2];
#pragma unroll
    for (int mt = 0; mt < 4; mt++)
#pragma unroll
        for (int nt = 0; nt < 2; nt++) {
            acck[mt][nt] = (f32x4){0.f, 0.f, 0.f, 0.f};
            accv[mt][nt] = (f32x4){0.f, 0.f, 0.f, 0.f};
        }

    for (int kk = 0; kk < 16; kk++) {
        int k0 = kk * 64;
#pragma unroll
        for (int i = 0; i < 2; i++) {
            int c = tid + i * 512;
            int row = c >> 3, c8 = c & 7;
            const float4* p = (const float4*)(xA + (size_t)row * DCH + k0 + c8 * 8);
            float4 f0 = p[0], f1 = p[1];
            unsigned int p0 = f2bf(f0.x) | (f2bf(f0.y) << 16);
            unsigned int p1 = f2bf(f0.z) | (f2bf(f0.w) << 16);
            unsigned int p2 = f2bf(f1.x) | (f2bf(f1.y) << 16);
            unsigned int p3 = f2bf(f1.z) | (f2bf(f1.w) << 16);
            uint4 pk = {p0, p1, p2, p3};
            int g = c8 ^ (row & 7);
            *((uint4*)&sA[row * 64 + g * 8]) = pk;
        }
#pragma unroll
        for (int i = 0; i < 2; i++) {
            int c = tid + i * 512;
            int row = c >> 3, c8 = c & 7;
            int g = c8 ^ (row & 7);
            *((uint4*)&sK[row * 64 + g * 8]) =
                *((const uint4*)(WkT + (size_t)(h0 + row) * DCH + k0 + c8 * 8));
            *((uint4*)&sV[row * 64 + g * 8]) =
                *((const uint4*)(WvT + (size_t)(h0 + row) * DCH + k0 + c8 * 8));
        }
        __syncthreads();
#pragma unroll
        for (int ks = 0; ks < 2; ks++) {
            bf16x8 af[4], bkf[2], bvf[2];
            int gg = ks * 4 + lhi;
#pragma unroll
            for (int mt = 0; mt < 4; mt++) {
                int rowa = wsg * 64 + mt * 16 + col;
                af[mt] = *((const bf16x8*)&sA[rowa * 64 + ((gg ^ (rowa & 7)) * 8)]);
            }
#pragma unroll
            for (int nt = 0; nt < 2; nt++) {
                int rowb = wh * 32 + nt * 16 + col;
                int o = rowb * 64 + ((gg ^ (rowb & 7)) * 8);
                bkf[nt] = *((const bf16x8*)&sK[o]);
                bvf[nt] = *((const bf16x8*)&sV[o]);
            }
#pragma unroll
            for (int mt = 0; mt < 4; mt++)
#pragma unroll
                for (int nt = 0; nt < 2; nt++) {
                    acck[mt][nt] = __builtin_amdgcn_mfma_f32_16x16x32_bf16(
                        af[mt], bkf[nt], acck[mt][nt], 0, 0, 0);
                    accv[mt][nt] = __builtin_amdgcn_mfma_f32_16x16x32_bf16(
                        af[mt], bvf[nt], accv[mt][nt], 0, 0, 0);
                }
        }
        __syncthreads();
    }

#pragma unroll
    for (int nt = 0; nt < 2; nt++) {
        int h_local = wh * 32 + nt * 16 + col;
        float bkv = bk[h0 + h_local];
        float bvv = bv[h0 + h_local];
        float pkv = 0.f, pks = 0.f;
#pragma unroll
        for (int mt = 0; mt < 4; mt++)
#pragma unroll
            for (int rr = 0; rr < 4; rr++) {
                float ck = acck[mt][nt][rr] + bkv;
                float cv = accv[mt][nt][rr] + bvv;
                float kq = ck > 0.f ? ck + 1.f : __expf(ck);
                pkv += kq * cv;
                pks += kq;
            }
        pkv += __shfl_xor(pkv, 16);
        pkv += __shfl_xor(pkv, 32);
        pks += __shfl_xor(pks, 16);
        pks += __shfl_xor(pks, 32);
        if (lhi == 0) {
            red[wsg][h_local][0] = pkv;
            red[wsg][h_local][1] = pks;
        }
    }
    __syncthreads();
    if (tid < 256) {
        int h = tid & 127, t = tid >> 7;
        float v = red[0][h][t] + red[1][h][t];
        part[(((size_t)(n * 8 + h_tile) * 2 + t) * 32 + s_tile) * 128 + h] = v;
    }
}

// -------- reduce partials -> V = KV/Ksum, then k-split GEMM vs Wo ------------
__global__ __launch_bounds__(256) void out_part_kernel(
    const float* __restrict__ part, const float* __restrict__ Wo,
    float* __restrict__ part2)
{
    __shared__ float skv[128], sks[128], vs[128];
    int n = blockIdx.x, kc = blockIdx.y, ob = blockIdx.z;
    int tid = threadIdx.x;
    int g = n * 8 + kc;
    {
        int h = tid & 127, t = tid >> 7;
        const float* base = part + ((size_t)g * 2 + t) * 32 * 128;
        float s = 0.f;
#pragma unroll 4
        for (int st = 0; st < 32; st++) s += base[st * 128 + h];
        if (t == 0) skv[h] = s; else sks[h] = s;
    }
    __syncthreads();
    if (tid < 128) vs[tid] = skv[tid] / sks[tid];
    __syncthreads();
    int o = ob * 256 + tid;
    float acc = 0.f;
#pragma unroll 8
    for (int k = 0; k < 128; k++)
        acc += vs[k] * Wo[(size_t)(kc * 128 + k) * DCH + o];
    part2[(size_t)g * DCH + o] = acc;
}

// ---------------- finish (k-split sum + bias + gelu) fused with broadcast ----
__global__ __launch_bounds__(256) void bcast_kernel(
    const float4* __restrict__ part2, const float4* __restrict__ bo,
    float4* __restrict__ out)
{
    int n = blockIdx.x >> 7;
    int sc = blockIdx.x & 127;
    int tid = threadIdx.x;  // one float4 column group
    float4 a = bo[tid];
#pragma unroll
    for (int kc = 0; kc < 8; kc++) {
        float4 p = part2[(size_t)(n * 8 + kc) * 256 + tid];
        a.x += p.x; a.y += p.y; a.z += p.z; a.w += p.w;
    }
    float4 v;
    v.x = gelu_tanh(a.x);
    v.y = gelu_tanh(a.y);
    v.z = gelu_tanh(a.z);
    v.w = gelu_tanh(a.w);
    size_t base = ((size_t)(n * SEQ) + (size_t)sc * 32) * 256 + tid;
#pragma unroll 4
    for (int s = 0; s < 32; s++)
        out[base + (size_t)s * 256] = v;
}

extern "C" void kernel_launch(void* const* d_in, const int* in_sizes, int n_in,
                              void* d_out, int out_size, void* d_ws, size_t ws_size,
                              hipStream_t stream) {
    const float* x  = (const float*)d_in[0];
    // Wq (d_in[1]) / bq (d_in[2]) cancel: Q>0 in V = Q*KV/(Q*Ksum + 1e-6)
    // up to <=5e-8 relative perturbation (validated: absmax 2.4e-4).
    const float* Wk = (const float*)d_in[3];
    const float* bk = (const float*)d_in[4];
    const float* Wv = (const float*)d_in[5];
    const float* bv = (const float*)d_in[6];
    const float* Wo = (const float*)d_in[7];
    const float* bo = (const float*)d_in[8];

    const size_t XB_BYTES = (size_t)NBATCH * SEQ * DCH * 2;   // 64 MB
    const size_t TAIL = (8u << 20);                            // WkT/WvT/part/part2
    bool fast = ws_size >= XB_BYTES + TAIL;

    char* ws = (char*)d_ws;
    unsigned short* xb = (unsigned short*)ws;                  // fast path only
    char* base = fast ? ws + XB_BYTES : ws;
    unsigned short* WkT = (unsigned short*)base;               // 2 MB bf16 [h][k]
    unsigned short* WvT = WkT + 1024 * 1024;                   // 2 MB
    float* part  = (float*)(base + 4 * 1024 * 1024);           // 2.5 MB partials
    float* part2 = part + 8 * 8 * 2 * 32 * 128;                // 256 KB

    wt_kernel<<<dim3(32, 32, 2), dim3(32, 8), 0, stream>>>(Wk, Wv, WkT, WvT);
    if (fast) {
        cvt_kernel<<<16384, 256, 0, stream>>>((const float4*)x, (uint4*)xb);
        kv_gemm_fast<<<2048, 512, 0, stream>>>(xb, WkT, WvT, bk, bv, part);
    } else {
        kv_gemm_slow<<<2048, 512, 0, stream>>>(x, WkT, WvT, bk, bv, part);
    }
    out_part_kernel<<<dim3(8, 8, 4), 256, 0, stream>>>(part, Wo, part2);
    bcast_kernel<<<1024, 256, 0, stream>>>((const float4*)part2, (const float4*)bo,
                                           (float4*)d_out);
}

// Round 5
// 419.141 us; speedup vs baseline: 1.2977x; 1.0838x over previous
//
#include <hip/hip_runtime.h>
#include <hip/hip_bf16.h>

typedef __attribute__((ext_vector_type(8))) short bf16x8;
typedef __attribute__((ext_vector_type(4))) float f32x4;

#define GLOBAL_AS __attribute__((address_space(1)))
#define LDS_AS __attribute__((address_space(3)))

#define DCH 1024
#define SEQ 4096
#define NBATCH 8

// RNE float -> bf16 (finite inputs)
static __device__ __forceinline__ unsigned int f2bf(float f) {
    unsigned int u = __float_as_uint(f);
    return (u + 0x7fffu + ((u >> 16) & 1u)) >> 16;
}

static __device__ __forceinline__ void async_copy16(const void* g, void* l) {
    __builtin_amdgcn_global_load_lds((const GLOBAL_AS void*)g, (LDS_AS void*)l, 16, 0, 0);
}

static __device__ __forceinline__ float gelu_tanh(float u) {
    float inner = 0.7978845608028654f * (u + 0.044715f * u * u * u);
    return 0.5f * u * (1.f + tanhf(inner));  // gelu approximate=True
}

// ---------------- x fp32 -> bf16 (once; amortized over h-tile re-reads) ------
__global__ __launch_bounds__(256) void cvt_kernel(
    const float4* __restrict__ x, uint4* __restrict__ xb)
{
    size_t t = (size_t)blockIdx.x * 256 + threadIdx.x;  // 4M threads, 8 floats each
    float4 f0 = x[t * 2], f1 = x[t * 2 + 1];
    uint4 a;
    a.x = f2bf(f0.x) | (f2bf(f0.y) << 16);
    a.y = f2bf(f0.z) | (f2bf(f0.w) << 16);
    a.z = f2bf(f1.x) | (f2bf(f1.y) << 16);
    a.w = f2bf(f1.z) | (f2bf(f1.w) << 16);
    xb[t] = a;
}

// ---------------- transpose + convert Wk/Wv -> bf16 W^T[h][k] ----------------
__global__ __launch_bounds__(256) void wt_kernel(
    const float* __restrict__ Wk, const float* __restrict__ Wv,
    unsigned short* __restrict__ WkT, unsigned short* __restrict__ WvT)
{
    __shared__ float tile[32][33];
    const float* src = blockIdx.z ? Wv : Wk;
    unsigned short* dst = blockIdx.z ? WvT : WkT;
    int h0 = blockIdx.x * 32, k0 = blockIdx.y * 32;
    int tx = threadIdx.x, ty = threadIdx.y;
#pragma unroll
    for (int i = 0; i < 4; i++)
        tile[ty + i * 8][tx] = src[(size_t)(k0 + ty + i * 8) * DCH + h0 + tx];
    __syncthreads();
#pragma unroll
    for (int i = 0; i < 4; i++)
        dst[(size_t)(h0 + ty + i * 8) * DCH + k0 + tx] =
            (unsigned short)f2bf(tile[tx][ty + i * 8]);
}

// ---------------- fast path: fused K/V projection + fmap + reduction ---------
// v2: 256-thread blocks (4 waves), tile 128 s x 64 h, BK=64. Same per-wave
// shape as the verified R2/R4 kernel (64s x 32h, acc 4x2x2 = 132 regs/wave ->
// 3 waves/SIMD), but the smaller block turns 12 waves/CU into THREE
// independent blocks/CU instead of one 8-wave block + 4 dead slots -- blocks
// overlap each other's barrier drains. A/K/V all staged via global_load_lds
// (16B) with source-column XOR swizzle (no plain global loads in the vmcnt
// queue -- the R3 direct-B variant raced under graph replay).
__global__ __launch_bounds__(256) void kv_gemm_fast(
    const unsigned short* __restrict__ xb,
    const unsigned short* __restrict__ WkT,
    const unsigned short* __restrict__ WvT,
    const float* __restrict__ bk,
    const float* __restrict__ bv,
    float* __restrict__ part)
{
    __shared__ unsigned short sA[128 * 64];
    __shared__ unsigned short sK[64 * 64];
    __shared__ unsigned short sV[64 * 64];
    __shared__ float red[2][64][2];

    // XCD swizzle: all 16 h-tiles of one (n,s_tile) land on the same XCD
    int b = blockIdx.x;
    int r = b & 7, j = b >> 3;
    int h_tile = j & 15;
    int ns = r * 32 + (j >> 4);
    int n = ns >> 5, s_tile = ns & 31;
    int s0 = s_tile * 128, h0 = h_tile * 64;

    int tid = threadIdx.x;
    int lane = tid & 63, wid = tid >> 6;     // 4 waves
    int wsg = wid >> 1, wh = wid & 1;        // 2 s-groups x 2 h-groups
    int col = lane & 15, lhi = lane >> 4;

    // A staging: 1024 16B chunks, 4 per thread: c = (wid*4+i)*64 + lane
    const unsigned short* gA[4];
    unsigned short* lA[4];
#pragma unroll
    for (int i = 0; i < 4; i++) {
        int c = (wid * 4 + i) * 64 + lane;
        int row = c >> 3, c8 = (c & 7) ^ (row & 7);
        gA[i] = xb + (size_t)(n * SEQ + s0 + row) * DCH + c8 * 8;
        lA[i] = &sA[(wid * 4 + i) * 512];
    }
    // K/V staging: 512 chunks each, 2 per thread: c = (wid*2+i)*64 + lane
    const unsigned short* gK[2];
    const unsigned short* gV[2];
    unsigned short* lK[2];
    unsigned short* lV[2];
#pragma unroll
    for (int i = 0; i < 2; i++) {
        int c = (wid * 2 + i) * 64 + lane;
        int row = c >> 3, c8 = (c & 7) ^ (row & 7);
        gK[i] = WkT + (size_t)(h0 + row) * DCH + c8 * 8;
        gV[i] = WvT + (size_t)(h0 + row) * DCH + c8 * 8;
        lK[i] = &sK[(wid * 2 + i) * 512];
        lV[i] = &sV[(wid * 2 + i) * 512];
    }

    f32x4 acck[4][2], accv[4][2];
#pragma unroll
    for (int mt = 0; mt < 4; mt++)
#pragma unroll
        for (int nt = 0; nt < 2; nt++) {
            acck[mt][nt] = (f32x4){0.f, 0.f, 0.f, 0.f};
            accv[mt][nt] = (f32x4){0.f, 0.f, 0.f, 0.f};
        }

    for (int kk = 0; kk < 16; kk++) {
        int k0 = kk * 64;
#pragma unroll
        for (int i = 0; i < 4; i++) async_copy16(gA[i] + k0, lA[i]);
#pragma unroll
        for (int i = 0; i < 2; i++) async_copy16(gK[i] + k0, lK[i]);
#pragma unroll
        for (int i = 0; i < 2; i++) async_copy16(gV[i] + k0, lV[i]);
        __syncthreads();
#pragma unroll
        for (int ks = 0; ks < 2; ks++) {
            bf16x8 af[4], bkf[2], bvf[2];
            int gg = ks * 4 + lhi;
#pragma unroll
            for (int mt = 0; mt < 4; mt++) {
                int rowa = wsg * 64 + mt * 16 + col;
                af[mt] = *((const bf16x8*)&sA[rowa * 64 + ((gg ^ (rowa & 7)) * 8)]);
            }
#pragma unroll
            for (int nt = 0; nt < 2; nt++) {
                int rowb = wh * 32 + nt * 16 + col;
                int o = rowb * 64 + ((gg ^ (rowb & 7)) * 8);
                bkf[nt] = *((const bf16x8*)&sK[o]);
                bvf[nt] = *((const bf16x8*)&sV[o]);
            }
#pragma unroll
            for (int mt = 0; mt < 4; mt++)
#pragma unroll
                for (int nt = 0; nt < 2; nt++) {
                    acck[mt][nt] = __builtin_amdgcn_mfma_f32_16x16x32_bf16(
                        af[mt], bkf[nt], acck[mt][nt], 0, 0, 0);
                    accv[mt][nt] = __builtin_amdgcn_mfma_f32_16x16x32_bf16(
                        af[mt], bvf[nt], accv[mt][nt], 0, 0, 0);
                }
        }
        __syncthreads();
    }

    // epilogue: fmap, pairwise product, reduce over the 128 s-rows of this tile
#pragma unroll
    for (int nt = 0; nt < 2; nt++) {
        int h_local = wh * 32 + nt * 16 + col;
        float bkv = bk[h0 + h_local];
        float bvv = bv[h0 + h_local];
        float pkv = 0.f, pks = 0.f;
#pragma unroll
        for (int mt = 0; mt < 4; mt++)
#pragma unroll
            for (int rr = 0; rr < 4; rr++) {
                float ck = acck[mt][nt][rr] + bkv;
                float cv = accv[mt][nt][rr] + bvv;
                float kq = ck > 0.f ? ck + 1.f : __expf(ck);  // elu+1
                pkv += kq * cv;
                pks += kq;
            }
        pkv += __shfl_xor(pkv, 16);
        pkv += __shfl_xor(pkv, 32);
        pks += __shfl_xor(pks, 16);
        pks += __shfl_xor(pks, 32);
        if (lhi == 0) {
            red[wsg][h_local][0] = pkv;
            red[wsg][h_local][1] = pks;
        }
    }
    __syncthreads();
    if (tid < 128) {
        int h = tid & 63, t = tid >> 6;
        float v = red[0][h][t] + red[1][h][t];
        part[(((size_t)(n * 16 + h_tile) * 2 + t) * 32 + s_tile) * 64 + h] = v;
    }
}

// ---------------- slow fallback (fp32 staging, no xb needed) -----------------
__global__ __launch_bounds__(512) void kv_gemm_slow(
    const float* __restrict__ x,
    const unsigned short* __restrict__ WkT,
    const unsigned short* __restrict__ WvT,
    const float* __restrict__ bk,
    const float* __restrict__ bv,
    float* __restrict__ part)
{
    __shared__ unsigned short sA[128 * 64];
    __shared__ unsigned short sK[128 * 64];
    __shared__ unsigned short sV[128 * 64];
    __shared__ float red[2][128][2];

    int b = blockIdx.x;
    int r = b & 7, j = b >> 3;
    int ns = r * 32 + (j >> 3);
    int h_tile = j & 7;
    int n = ns >> 5, s_tile = ns & 31;
    int s0 = s_tile * 128, h0 = h_tile * 128;

    const float* xA = x + ((size_t)(n * SEQ + s0)) * DCH;

    int tid = threadIdx.x;
    int lane = tid & 63, wid = tid >> 6;
    int wsg = wid >> 2, wh = wid & 3;
    int col = lane & 15, lhi = lane >> 4;

    f32x4 acck[4][2], accv[4][2];
#pragma unroll
    for (int mt = 0; mt < 4; mt++)
#pragma unroll
        for (int nt = 0; nt < 2; nt++) {
            acck[mt][nt] = (f32x4){0.f, 0.f, 0.f, 0.f};
            accv[mt][nt] = (f32x4){0.f, 0.f, 0.f, 0.f};
        }

    for (int kk = 0; kk < 16; kk++) {
        int k0 = kk * 64;
#pragma unroll
        for (int i = 0; i < 2; i++) {
            int c = tid + i * 512;
            int row = c >> 3, c8 = c & 7;
            const float4* p = (const float4*)(xA + (size_t)row * DCH + k0 + c8 * 8);
            float4 f0 = p[0], f1 = p[1];
            unsigned int p0 = f2bf(f0.x) | (f2bf(f0.y) << 16);
            unsigned int p1 = f2bf(f0.z) | (f2bf(f0.w) << 16);
            unsigned int p2 = f2bf(f1.x) | (f2bf(f1.y) << 16);
            unsigned int p3 = f2bf(f1.z) | (f2bf(f1.w) << 16);
            uint4 pk = {p0, p1, p2, p3};
            int g = c8 ^ (row & 7);
            *((uint4*)&sA[row * 64 + g * 8]) = pk;
        }
#pragma unroll
        for (int i = 0; i < 2; i++) {
            int c = tid + i * 512;
            int row = c >> 3, c8 = c & 7;
            int g = c8 ^ (row & 7);
            *((uint4*)&sK[row * 64 + g * 8]) =
                *((const uint4*)(WkT + (size_t)(h0 + row) * DCH + k0 + c8 * 8));
            *((uint4*)&sV[row * 64 + g * 8]) =
                *((const uint4*)(WvT + (size_t)(h0 + row) * DCH + k0 + c8 * 8));
        }
        __syncthreads();
#pragma unroll
        for (int ks = 0; ks < 2; ks++) {
            bf16x8 af[4], bkf[2], bvf[2];
            int gg = ks * 4 + lhi;
#pragma unroll
            for (int mt = 0; mt < 4; mt++) {
                int rowa = wsg * 64 + mt * 16 + col;
                af[mt] = *((const bf16x8*)&sA[rowa * 64 + ((gg ^ (rowa & 7)) * 8)]);
            }
#pragma unroll
            for (int nt = 0; nt < 2; nt++) {
                int rowb = wh * 32 + nt * 16 + col;
                int o = rowb * 64 + ((gg ^ (rowb & 7)) * 8);
                bkf[nt] = *((const bf16x8*)&sK[o]);
                bvf[nt] = *((const bf16x8*)&sV[o]);
            }
#pragma unroll
            for (int mt = 0; mt < 4; mt++)
#pragma unroll
                for (int nt = 0; nt < 2; nt++) {
                    acck[mt][nt] = __builtin_amdgcn_mfma_f32_16x16x32_bf16(
                        af[mt], bkf[nt], acck[mt][nt], 0, 0, 0);
                    accv[mt][nt] = __builtin_amdgcn_mfma_f32_16x16x32_bf16(
                        af[mt], bvf[nt], accv[mt][nt], 0, 0, 0);
                }
        }
        __syncthreads();
    }

#pragma unroll
    for (int nt = 0; nt < 2; nt++) {
        int h_local = wh * 32 + nt * 16 + col;
        float bkv = bk[h0 + h_local];
        float bvv = bv[h0 + h_local];
        float pkv = 0.f, pks = 0.f;
#pragma unroll
        for (int mt = 0; mt < 4; mt++)
#pragma unroll
            for (int rr = 0; rr < 4; rr++) {
                float ck = acck[mt][nt][rr] + bkv;
                float cv = accv[mt][nt][rr] + bvv;
                float kq = ck > 0.f ? ck + 1.f : __expf(ck);
                pkv += kq * cv;
                pks += kq;
            }
        pkv += __shfl_xor(pkv, 16);
        pkv += __shfl_xor(pkv, 32);
        pks += __shfl_xor(pks, 16);
        pks += __shfl_xor(pks, 32);
        if (lhi == 0) {
            red[wsg][h_local][0] = pkv;
            red[wsg][h_local][1] = pks;
        }
    }
    __syncthreads();
    if (tid < 256) {
        int h = tid & 127, t = tid >> 7;
        float v = red[0][h][t] + red[1][h][t];
        // new part layout: 16 h-tiles of 64 channels
        int ht = h_tile * 2 + (h >> 6);
        part[(((size_t)(n * 16 + ht) * 2 + t) * 32 + s_tile) * 64 + (h & 63)] = v;
    }
}

// -------- reduce partials -> V = KV/Ksum, then k-split GEMM vs Wo ------------
__global__ __launch_bounds__(256) void out_part_kernel(
    const float* __restrict__ part, const float* __restrict__ Wo,
    float* __restrict__ part2)
{
    __shared__ float skv[128], sks[128], vs[128];
    int n = blockIdx.x, kc = blockIdx.y, ob = blockIdx.z;
    int tid = threadIdx.x;
    {
        int h = tid & 127, t = tid >> 7;
        int ht = kc * 2 + (h >> 6);
        const float* base = part + (((size_t)(n * 16 + ht) * 2 + t) * 32) * 64;
        float s = 0.f;
#pragma unroll 4
        for (int st = 0; st < 32; st++) s += base[st * 64 + (h & 63)];
        if (t == 0) skv[h] = s; else sks[h] = s;
    }
    __syncthreads();
    if (tid < 128) vs[tid] = skv[tid] / sks[tid];
    __syncthreads();
    int o = ob * 256 + tid;
    float acc = 0.f;
#pragma unroll 8
    for (int k = 0; k < 128; k++)
        acc += vs[k] * Wo[(size_t)(kc * 128 + k) * DCH + o];
    part2[(size_t)(n * 8 + kc) * DCH + o] = acc;
}

// ---------------- finish (k-split sum + bias + gelu) fused with broadcast ----
__global__ __launch_bounds__(256) void bcast_kernel(
    const float4* __restrict__ part2, const float4* __restrict__ bo,
    float4* __restrict__ out)
{
    int n = blockIdx.x >> 7;
    int sc = blockIdx.x & 127;
    int tid = threadIdx.x;  // one float4 column group
    float4 a = bo[tid];
#pragma unroll
    for (int kc = 0; kc < 8; kc++) {
        float4 p = part2[(size_t)(n * 8 + kc) * 256 + tid];
        a.x += p.x; a.y += p.y; a.z += p.z; a.w += p.w;
    }
    float4 v;
    v.x = gelu_tanh(a.x);
    v.y = gelu_tanh(a.y);
    v.z = gelu_tanh(a.z);
    v.w = gelu_tanh(a.w);
    size_t base = ((size_t)(n * SEQ) + (size_t)sc * 32) * 256 + tid;
#pragma unroll 4
    for (int s = 0; s < 32; s++)
        out[base + (size_t)s * 256] = v;
}

extern "C" void kernel_launch(void* const* d_in, const int* in_sizes, int n_in,
                              void* d_out, int out_size, void* d_ws, size_t ws_size,
                              hipStream_t stream) {
    const float* x  = (const float*)d_in[0];
    // Wq (d_in[1]) / bq (d_in[2]) cancel: Q>0 in V = Q*KV/(Q*Ksum + 1e-6)
    // up to <=5e-8 relative perturbation (validated: absmax 2.4e-4).
    const float* Wk = (const float*)d_in[3];
    const float* bk = (const float*)d_in[4];
    const float* Wv = (const float*)d_in[5];
    const float* bv = (const float*)d_in[6];
    const float* Wo = (const float*)d_in[7];
    const float* bo = (const float*)d_in[8];

    const size_t XB_BYTES = (size_t)NBATCH * SEQ * DCH * 2;       // 64 MB
    // tail: WkT(2M) + WvT(2M) + part(8M) + part2(512K)
    const size_t TAIL = (4u << 20) + (8u << 20) + (1u << 19);
    bool fast = ws_size >= XB_BYTES + TAIL;

    char* ws = (char*)d_ws;
    unsigned short* xb = (unsigned short*)ws;                  // fast path only
    char* base = fast ? ws + XB_BYTES : ws;
    unsigned short* WkT = (unsigned short*)base;               // 2 MB bf16 [h][k]
    unsigned short* WvT = WkT + 1024 * 1024;                   // 2 MB
    float* part  = (float*)(base + 4 * 1024 * 1024);           // 8 MB partials
    float* part2 = part + (size_t)8 * 16 * 2 * 32 * 64;        // 512 KB

    wt_kernel<<<dim3(32, 32, 2), dim3(32, 8), 0, stream>>>(Wk, Wv, WkT, WvT);
    if (fast) {
        cvt_kernel<<<16384, 256, 0, stream>>>((const float4*)x, (uint4*)xb);
        kv_gemm_fast<<<4096, 256, 0, stream>>>(xb, WkT, WvT, bk, bv, part);
    } else {
        kv_gemm_slow<<<2048, 512, 0, stream>>>(x, WkT, WvT, bk, bv, part);
    }
    out_part_kernel<<<dim3(8, 8, 4), 256, 0, stream>>>(part, Wo, part2);
    bcast_kernel<<<1024, 256, 0, stream>>>((const float4*)part2, (const float4*)bo,
                                           (float4*)d_out);
}